// Round 3
// baseline (190.006 us; speedup 1.0000x reference)
//
#include <hip/hip_runtime.h>
#include <hip/hip_fp16.h>
#include <stdint.h>

// Problem constants (from reference setup_inputs)
#define BATCH 256
#define PSEL  128
#define IN_DIM 3200
#define O1_DIM 8192
#define O3_DIM 4096

// ---------------------------------------------------------------------------
// transpose x [256, 3200] fp32 -> xT [3200, 256] fp16
// Fused: zero the 4 x 256 float stats accumulators.
// xT store stays CACHEABLE: it is p1's gather table.
// ---------------------------------------------------------------------------
__global__ __launch_bounds__(256) void transpose_kernel(const float* __restrict__ x,
                                                        __half* __restrict__ xT,
                                                        float* __restrict__ stats) {
    int tx = threadIdx.x;       // 32
    int ty = threadIdx.y;       // 8
    int tid = ty * 32 + tx;
    int gid = blockIdx.y * gridDim.x + blockIdx.x;   // 0..799
    if (gid < 4) stats[gid * 256 + tid] = 0.0f;

    __shared__ float tile[32][33];
    int i0 = blockIdx.x * 32;   // input-dim tile (3200/32 = 100)
    int b0 = blockIdx.y * 32;   // batch tile    (256/32 = 8)
#pragma unroll
    for (int k = 0; k < 4; ++k)
        tile[ty + k * 8][tx] =
            __builtin_nontemporal_load(&x[(size_t)(b0 + ty + k * 8) * IN_DIM + i0 + tx]);
    __syncthreads();
#pragma unroll
    for (int k = 0; k < 4; ++k)
        xT[(size_t)(i0 + ty + k * 8) * BATCH + b0 + tx] =
            __float2half(tile[tx][ty + k * 8]);
}

// ---------------------------------------------------------------------------
// stats: per-batch-column sum / sum-of-squares of hT [8192, 256] fp16.
// 64 blocks x 128 rows; 8-deep load batches; LDS row-half combine; 4 atomics
// per column per block (64 same-address updates @~50ns = ~3us).
// Loads stay cacheable: the h table is the NEXT layer's gather target —
// this pass warms L2/L3 for it.
// ---------------------------------------------------------------------------
__global__ __launch_bounds__(256) void stats_kernel(const __half* __restrict__ hT,
                                                    float* __restrict__ gsum,
                                                    float* __restrict__ gsq) {
    int t   = threadIdx.x;
    int col = t & 127;          // dword column (batch 2col, 2col+1)
    int rp  = t >> 7;           // row half
    int r0  = blockIdx.x * 128 + rp * 64;
    const uint32_t* p = (const uint32_t*)hT + (size_t)r0 * 128 + col;
    float s0 = 0.f, s1 = 0.f, q0 = 0.f, q1 = 0.f;
#pragma unroll
    for (int ob = 0; ob < 8; ++ob) {
        uint32_t d[8];
#pragma unroll
        for (int j = 0; j < 8; ++j) d[j] = p[(size_t)(ob * 8 + j) * 128];
#pragma unroll
        for (int j = 0; j < 8; ++j) {
            float2 f = __half22float2(*(const __half2*)&d[j]);
            s0 += f.x; q0 = fmaf(f.x, f.x, q0);
            s1 += f.y; q1 = fmaf(f.y, f.y, q1);
        }
    }
    __shared__ float4 s_red[128];
    if (rp == 1) s_red[col] = make_float4(s0, s1, q0, q1);
    __syncthreads();
    if (rp == 0) {
        float4 r = s_red[col];
        atomicAdd(&gsum[2 * col],     s0 + r.x);
        atomicAdd(&gsum[2 * col + 1], s1 + r.y);
        atomicAdd(&gsq[2 * col],      q0 + r.z);
        atomicAdd(&gsq[2 * col + 1],  q1 + r.w);
    }
}

// ---------------------------------------------------------------------------
// popcnt layer: one block (256 threads) per output o.
// Thread t: 16B chunk cw = t&31 (batch elems 8cw..8cw+7), row-group rg = t>>5.
// Gather = 16 dwordx4 loads per thread, all issued before first consume
// (16 in flight/wave; 16 waves/CU -> 256 outstanding/CU).
// THIS ROUND: all streaming traffic is NON-TEMPORAL (sel/w loads were
// already nt; output stores now nt too). Only the gather table competes
// for L2 residency -> gathers should be served at L2 rate, not L3 rate.
// NT output stores also kill the 8x WRITE_SIZE write-allocate inflation
// seen in round 0 (32 MB written for a 4 MB logical output).
// Input layernorm folded algebraically: z = rs*acc + sumC - rs*mu*sumA - b.
// ---------------------------------------------------------------------------
template <bool NORM>
__global__ __launch_bounds__(256, 4) void popcnt_kernel(
    const __half* __restrict__ actT,  // [Nin, 256] fp16, rows = 512 B
    const int* __restrict__ sel,      // [Nout, 128]
    const float* __restrict__ w,      // [Nout, 128]
    const float* __restrict__ bias,   // [Nout]
    const float* __restrict__ g,      // [Nin]  (NORM only)
    const float* __restrict__ be,     // [Nin]  (NORM only)
    const float* __restrict__ gsum,   // [256]  (NORM only)
    const float* __restrict__ gsq,    // [256]  (NORM only)
    float inv_n,                      // 1/Nin  (NORM only)
    __half* __restrict__ outp)        // [Nout, 256] fp16
{
    const int o  = blockIdx.x;
    const int t  = threadIdx.x;       // 0..255
    const int cw = t & 31;            // 16-byte chunk within row
    const int rg = t >> 5;            // row group 0..7

    __shared__ uint32_t s_off[PSEL];          // byte offsets (idx*512)
    __shared__ float    s_A[PSEL];            // folded weights
    __shared__ float s_rA[PSEL], s_rC[PSEL];
    __shared__ float s_acc[8][264];           // padded: stride 264 -> 2-way max
    __shared__ float s_sums[2];

    if (t < PSEL) {
        int idx  = __builtin_nontemporal_load(&sel[o * PSEL + t]);
        float ww = __builtin_nontemporal_load(&w[o * PSEL + t]);
        float sw = 1.0f / (1.0f + __expf(-ww));   // resilu(w) == sigmoid(w)
        float a, c;
        if (NORM) { a = sw * g[idx]; c = sw * be[idx]; }
        else      { a = sw;          c = 0.0f; }
        s_off[t] = (uint32_t)idx << 9;            // idx * 512 B rows
        s_A[t]   = a;
        if (NORM) { s_rA[t] = a; s_rC[t] = c; }
    }
    __syncthreads();

    if (NORM && t < 64) {             // wave 0 reduces sumA, sumC over 128 entries
        float va = s_rA[t] + s_rA[t + 64];
        float vc = s_rC[t] + s_rC[t + 64];
#pragma unroll
        for (int off = 32; off > 0; off >>= 1) {
            va += __shfl_down(va, off, 64);
            vc += __shfl_down(vc, off, 64);
        }
        if (t == 0) { s_sums[0] = va; s_sums[1] = vc; }
    }

    // ---- gather: 16 dwordx4 loads, all in flight before first use ----
    // These stay CACHEABLE — the table is the one thing we want in L2.
    const char* base = (const char*)actT + (cw << 4);
    uint32_t off[16];
#pragma unroll
    for (int j = 0; j < 16; ++j)
        off[j] = s_off[j * 8 + rg];               // 2 distinct addrs/wave: bcast
    uint4 d[16];
#pragma unroll
    for (int j = 0; j < 16; ++j)
        d[j] = *(const uint4*)(base + off[j]);    // 16 loads in flight
    float acc[8] = {0.f, 0.f, 0.f, 0.f, 0.f, 0.f, 0.f, 0.f};
#pragma unroll
    for (int j = 0; j < 16; ++j) {
        float A = s_A[j * 8 + rg];
        const __half2* hp = (const __half2*)&d[j];
        float2 f0 = __half22float2(hp[0]);
        float2 f1 = __half22float2(hp[1]);
        float2 f2 = __half22float2(hp[2]);
        float2 f3 = __half22float2(hp[3]);
        acc[0] = fmaf(A, f0.x, acc[0]);
        acc[1] = fmaf(A, f0.y, acc[1]);
        acc[2] = fmaf(A, f1.x, acc[2]);
        acc[3] = fmaf(A, f1.y, acc[3]);
        acc[4] = fmaf(A, f2.x, acc[4]);
        acc[5] = fmaf(A, f2.y, acc[5]);
        acc[6] = fmaf(A, f3.x, acc[6]);
        acc[7] = fmaf(A, f3.y, acc[7]);
    }

    // ---- combine 8 row-groups: thread (cw,rg) owns batch 8cw..8cw+7 ----
    *(float4*)&s_acc[rg][8 * cw]     = make_float4(acc[0], acc[1], acc[2], acc[3]);
    *(float4*)&s_acc[rg][8 * cw + 4] = make_float4(acc[4], acc[5], acc[6], acc[7]);
    __syncthreads();   // also publishes s_sums

    float ab = 0.0f;
#pragma unroll
    for (int r = 0; r < 8; ++r) ab += s_acc[r][t];   // bank = (8r+t)%32: 2-way, free

    float bo = bias[o];
    float z;
    if (NORM) {
        float m  = gsum[t] * inv_n;
        float q  = gsq[t] * inv_n;
        float rs = rsqrtf(q - m * m + 1e-12f);
        z = rs * ab + s_sums[1] - rs * m * s_sums[0] - bo;
    } else {
        z = ab - bo;
    }
    float h = 1.0f / (1.0f + __expf(-z));
    // NT store: don't let the output stream evict the gather table from L2.
    __builtin_nontemporal_store(__half_as_ushort(__float2half(h)),
                                (unsigned short*)outp + (size_t)o * BATCH + t);
}

// ---------------------------------------------------------------------------
// final group-sum: out[b, g] = sum_{j<16} h3[16g+j, b] - 8.
// h3 is never re-read and out is never read: all NT.
// ---------------------------------------------------------------------------
__global__ __launch_bounds__(256) void final_reduce(const __half* __restrict__ h3T,
                                                    float* __restrict__ out) {
    int gidx = blockIdx.x;     // group 0..255
    int b    = threadIdx.x;    // batch 0..255
    const unsigned short* p = (const unsigned short*)h3T + (size_t)gidx * 16 * BATCH + b;
    float s = -8.0f;
#pragma unroll
    for (int j = 0; j < 16; ++j)
        s += __half2float(__ushort_as_half(__builtin_nontemporal_load(p + j * BATCH)));
    __builtin_nontemporal_store(s, &out[(size_t)b * 256 + gidx]);
}

// ---------------------------------------------------------------------------
extern "C" void kernel_launch(void* const* d_in, const int* in_sizes, int n_in,
                              void* d_out, int out_size, void* d_ws, size_t ws_size,
                              hipStream_t stream) {
    const float* x    = (const float*)d_in[0];
    const int*   sel1 = (const int*)d_in[1];
    const float* w1   = (const float*)d_in[2];
    const float* b1   = (const float*)d_in[3];
    const float* g1   = (const float*)d_in[4];
    const float* be1  = (const float*)d_in[5];
    const int*   sel2 = (const int*)d_in[6];
    const float* w2   = (const float*)d_in[7];
    const float* b2   = (const float*)d_in[8];
    const float* g2   = (const float*)d_in[9];
    const float* be2  = (const float*)d_in[10];
    const int*   sel3 = (const int*)d_in[11];
    const float* w3   = (const float*)d_in[12];
    const float* b3   = (const float*)d_in[13];
    float* out = (float*)d_out;

    // workspace layout (fp16 activations); h3T reuses h1T (dead after layer 2)
    char* ws = (char*)d_ws;
    __half* xT  = (__half*)(ws);                          // 3200*256*2 = 1,638,400
    __half* h1T = (__half*)(ws + 1638400);                // 8192*256*2 = 4,194,304
    __half* h2T = (__half*)(ws + 1638400 + 4194304);      // 4,194,304
    __half* h3T = h1T;                                    // 4096*256*2 = 2,097,152
    float* stats = (float*)(ws + 1638400 + 2 * 4194304);  // 4 * 256 floats
    float* gs1 = stats;
    float* gq1 = stats + 256;
    float* gs2 = stats + 512;
    float* gq2 = stats + 768;

    // transpose + stats zero-init fused
    transpose_kernel<<<dim3(IN_DIM / 32, BATCH / 32), dim3(32, 8), 0, stream>>>(
        x, xT, stats);

    // Layer 1: x -> h1 (no input norm)
    popcnt_kernel<false><<<O1_DIM, 256, 0, stream>>>(
        xT, sel1, w1, b1, nullptr, nullptr, nullptr, nullptr, 0.0f, h1T);

    // stats of h1 for layernorm 1
    stats_kernel<<<O1_DIM / 128, 256, 0, stream>>>(h1T, gs1, gq1);

    // Layer 2: layernorm(h1) folded in
    popcnt_kernel<true><<<O1_DIM, 256, 0, stream>>>(
        h1T, sel2, w2, b2, g1, be1, gs1, gq1, 1.0f / (float)O1_DIM, h2T);

    // stats of h2 for layernorm 2
    stats_kernel<<<O1_DIM / 128, 256, 0, stream>>>(h2T, gs2, gq2);

    // Layer 3: layernorm(h2) folded in, writes h3 rows (no atomics)
    popcnt_kernel<true><<<O3_DIM, 256, 0, stream>>>(
        h2T, sel3, w3, b3, g2, be2, gs2, gq2, 1.0f / (float)O1_DIM, h3T);

    // final 16-wide group sum - 8
    final_reduce<<<256, 256, 0, stream>>>(h3T, out);
}

// Round 4
// 181.604 us; speedup vs baseline: 1.0463x; 1.0463x over previous
//
#include <hip/hip_runtime.h>
#include <hip/hip_fp16.h>
#include <stdint.h>

// Problem constants (from reference setup_inputs)
#define BATCH 256
#define PSEL  128
#define IN_DIM 3200
#define O1_DIM 8192
#define O3_DIM 4096

// ---------------------------------------------------------------------------
// transpose x [256, 3200] fp32 -> xT [3200, 256] fp16
// Fused: zero the 4 x 256 float stats accumulators.
// xT store stays CACHEABLE: it is p1's gather table.
// ---------------------------------------------------------------------------
__global__ __launch_bounds__(256) void transpose_kernel(const float* __restrict__ x,
                                                        __half* __restrict__ xT,
                                                        float* __restrict__ stats) {
    int tx = threadIdx.x;       // 32
    int ty = threadIdx.y;       // 8
    int tid = ty * 32 + tx;
    int gid = blockIdx.y * gridDim.x + blockIdx.x;   // 0..799
    if (gid < 4) stats[gid * 256 + tid] = 0.0f;

    __shared__ float tile[32][33];
    int i0 = blockIdx.x * 32;   // input-dim tile (3200/32 = 100)
    int b0 = blockIdx.y * 32;   // batch tile    (256/32 = 8)
#pragma unroll
    for (int k = 0; k < 4; ++k)
        tile[ty + k * 8][tx] =
            __builtin_nontemporal_load(&x[(size_t)(b0 + ty + k * 8) * IN_DIM + i0 + tx]);
    __syncthreads();
#pragma unroll
    for (int k = 0; k < 4; ++k)
        xT[(size_t)(i0 + ty + k * 8) * BATCH + b0 + tx] =
            __float2half(tile[tx][ty + k * 8]);
}

// ---------------------------------------------------------------------------
// stats: per-batch-column sum / sum-of-squares of hT [8192, 256] fp16.
// 64 blocks x 128 rows; 8-deep load batches; LDS row-half combine; 4 atomics
// per column per block (64 same-address updates @~50ns = ~3us).
// ---------------------------------------------------------------------------
__global__ __launch_bounds__(256) void stats_kernel(const __half* __restrict__ hT,
                                                    float* __restrict__ gsum,
                                                    float* __restrict__ gsq) {
    int t   = threadIdx.x;
    int col = t & 127;          // dword column (batch 2col, 2col+1)
    int rp  = t >> 7;           // row half
    int r0  = blockIdx.x * 128 + rp * 64;
    const uint32_t* p = (const uint32_t*)hT + (size_t)r0 * 128 + col;
    float s0 = 0.f, s1 = 0.f, q0 = 0.f, q1 = 0.f;
#pragma unroll
    for (int ob = 0; ob < 8; ++ob) {
        uint32_t d[8];
#pragma unroll
        for (int j = 0; j < 8; ++j) d[j] = p[(size_t)(ob * 8 + j) * 128];
#pragma unroll
        for (int j = 0; j < 8; ++j) {
            float2 f = __half22float2(*(const __half2*)&d[j]);
            s0 += f.x; q0 = fmaf(f.x, f.x, q0);
            s1 += f.y; q1 = fmaf(f.y, f.y, q1);
        }
    }
    __shared__ float4 s_red[128];
    if (rp == 1) s_red[col] = make_float4(s0, s1, q0, q1);
    __syncthreads();
    if (rp == 0) {
        float4 r = s_red[col];
        atomicAdd(&gsum[2 * col],     s0 + r.x);
        atomicAdd(&gsum[2 * col + 1], s1 + r.y);
        atomicAdd(&gsq[2 * col],      q0 + r.z);
        atomicAdd(&gsq[2 * col + 1],  q1 + r.w);
    }
}

// ---------------------------------------------------------------------------
// popcnt layer: one block (256 threads) per output o.
// Thread t: 16B chunk cw = t&31 (batch elems 8cw..8cw+7), row-group rg = t>>5.
// THIS ROUND: gather loads are issued as inline-asm global_load_dwordx4 with
// sc0 (agent scope) -> bypass the 32KB L0/L1 lookup+allocate and serve from
// L2 directly (still L2-cached, unlike nt). Theory: the gather is service-
// rate-limited at ~20 B/cy/CU by the L1 line-allocate path (~3 cy/line on
// ~100% miss traffic); sc0 removes that stage. SGPR-base + 32b voffset form
// keeps address pressure at 1 VGPR/load. Explicit vmcnt(0) + sched_barrier
// fence before consumption (compiler doesn't track asm loads).
// Input layernorm folded algebraically: z = rs*acc + sumC - rs*mu*sumA - b.
// ---------------------------------------------------------------------------
template <bool NORM>
__global__ __launch_bounds__(256, 4) void popcnt_kernel(
    const __half* __restrict__ actT,  // [Nin, 256] fp16, rows = 512 B
    const int* __restrict__ sel,      // [Nout, 128]
    const float* __restrict__ w,      // [Nout, 128]
    const float* __restrict__ bias,   // [Nout]
    const float* __restrict__ g,      // [Nin]  (NORM only)
    const float* __restrict__ be,     // [Nin]  (NORM only)
    const float* __restrict__ gsum,   // [256]  (NORM only)
    const float* __restrict__ gsq,    // [256]  (NORM only)
    float inv_n,                      // 1/Nin  (NORM only)
    __half* __restrict__ outp)        // [Nout, 256] fp16
{
    const int o  = blockIdx.x;
    const int t  = threadIdx.x;       // 0..255
    const int cw = t & 31;            // 16-byte chunk within row
    const int rg = t >> 5;            // row group 0..7

    __shared__ uint32_t s_off[PSEL];          // byte offsets (idx*512)
    __shared__ float    s_A[PSEL];            // folded weights
    __shared__ float s_rA[PSEL], s_rC[PSEL];
    __shared__ float s_acc[8][264];           // padded: stride 264 -> 2-way max
    __shared__ float s_sums[2];

    if (t < PSEL) {
        int idx  = __builtin_nontemporal_load(&sel[o * PSEL + t]);
        float ww = __builtin_nontemporal_load(&w[o * PSEL + t]);
        float sw = 1.0f / (1.0f + __expf(-ww));   // resilu(w) == sigmoid(w)
        float a, c;
        if (NORM) { a = sw * g[idx]; c = sw * be[idx]; }
        else      { a = sw;          c = 0.0f; }
        s_off[t] = (uint32_t)idx << 9;            // idx * 512 B rows
        s_A[t]   = a;
        if (NORM) { s_rA[t] = a; s_rC[t] = c; }
    }
    __syncthreads();

    if (NORM && t < 64) {             // wave 0 reduces sumA, sumC over 128 entries
        float va = s_rA[t] + s_rA[t + 64];
        float vc = s_rC[t] + s_rC[t + 64];
#pragma unroll
        for (int off = 32; off > 0; off >>= 1) {
            va += __shfl_down(va, off, 64);
            vc += __shfl_down(vc, off, 64);
        }
        if (t == 0) { s_sums[0] = va; s_sums[1] = vc; }
    }

    // ---- gather: 16 L1-bypass (sc0) dwordx4 loads, all in flight ----
    const uint32_t lane_off = (uint32_t)(cw << 4);
    uint32_t voff[16];
#pragma unroll
    for (int j = 0; j < 16; ++j)
        voff[j] = s_off[j * 8 + rg] + lane_off;   // 2 distinct rows/wave: bcast
    uint4 d[16];
#pragma unroll
    for (int j = 0; j < 16; ++j)
        asm volatile("global_load_dwordx4 %0, %1, %2 sc0"
                     : "=v"(d[j])
                     : "v"(voff[j]), "s"(actT)
                     : "memory");
    asm volatile("s_waitcnt vmcnt(0)" ::: "memory");
    __builtin_amdgcn_sched_barrier(0);

    float acc[8] = {0.f, 0.f, 0.f, 0.f, 0.f, 0.f, 0.f, 0.f};
#pragma unroll
    for (int j = 0; j < 16; ++j) {
        float A = s_A[j * 8 + rg];
        const __half2* hp = (const __half2*)&d[j];
        float2 f0 = __half22float2(hp[0]);
        float2 f1 = __half22float2(hp[1]);
        float2 f2 = __half22float2(hp[2]);
        float2 f3 = __half22float2(hp[3]);
        acc[0] = fmaf(A, f0.x, acc[0]);
        acc[1] = fmaf(A, f0.y, acc[1]);
        acc[2] = fmaf(A, f1.x, acc[2]);
        acc[3] = fmaf(A, f1.y, acc[3]);
        acc[4] = fmaf(A, f2.x, acc[4]);
        acc[5] = fmaf(A, f2.y, acc[5]);
        acc[6] = fmaf(A, f3.x, acc[6]);
        acc[7] = fmaf(A, f3.y, acc[7]);
    }

    // ---- combine 8 row-groups: thread (cw,rg) owns batch 8cw..8cw+7 ----
    *(float4*)&s_acc[rg][8 * cw]     = make_float4(acc[0], acc[1], acc[2], acc[3]);
    *(float4*)&s_acc[rg][8 * cw + 4] = make_float4(acc[4], acc[5], acc[6], acc[7]);
    __syncthreads();   // also publishes s_sums

    float ab = 0.0f;
#pragma unroll
    for (int r = 0; r < 8; ++r) ab += s_acc[r][t];   // bank = (8r+t)%32: 2-way, free

    float bo = bias[o];
    float z;
    if (NORM) {
        float m  = gsum[t] * inv_n;
        float q  = gsq[t] * inv_n;
        float rs = rsqrtf(q - m * m + 1e-12f);
        z = rs * ab + s_sums[1] - rs * m * s_sums[0] - bo;
    } else {
        z = ab - bo;
    }
    float h = 1.0f / (1.0f + __expf(-z));
    // NT store: streaming output, never re-read by this kernel.
    __builtin_nontemporal_store(__half_as_ushort(__float2half(h)),
                                (unsigned short*)outp + (size_t)o * BATCH + t);
}

// ---------------------------------------------------------------------------
// final group-sum: out[b, g] = sum_{j<16} h3[16g+j, b] - 8.
// ---------------------------------------------------------------------------
__global__ __launch_bounds__(256) void final_reduce(const __half* __restrict__ h3T,
                                                    float* __restrict__ out) {
    int gidx = blockIdx.x;     // group 0..255
    int b    = threadIdx.x;    // batch 0..255
    const unsigned short* p = (const unsigned short*)h3T + (size_t)gidx * 16 * BATCH + b;
    float s = -8.0f;
#pragma unroll
    for (int j = 0; j < 16; ++j)
        s += __half2float(__ushort_as_half(__builtin_nontemporal_load(p + j * BATCH)));
    __builtin_nontemporal_store(s, &out[(size_t)b * 256 + gidx]);
}

// ---------------------------------------------------------------------------
extern "C" void kernel_launch(void* const* d_in, const int* in_sizes, int n_in,
                              void* d_out, int out_size, void* d_ws, size_t ws_size,
                              hipStream_t stream) {
    const float* x    = (const float*)d_in[0];
    const int*   sel1 = (const int*)d_in[1];
    const float* w1   = (const float*)d_in[2];
    const float* b1   = (const float*)d_in[3];
    const float* g1   = (const float*)d_in[4];
    const float* be1  = (const float*)d_in[5];
    const int*   sel2 = (const int*)d_in[6];
    const float* w2   = (const float*)d_in[7];
    const float* b2   = (const float*)d_in[8];
    const float* g2   = (const float*)d_in[9];
    const float* be2  = (const float*)d_in[10];
    const int*   sel3 = (const int*)d_in[11];
    const float* w3   = (const float*)d_in[12];
    const float* b3   = (const float*)d_in[13];
    float* out = (float*)d_out;

    // workspace layout (fp16 activations); h3T reuses h1T (dead after layer 2)
    char* ws = (char*)d_ws;
    __half* xT  = (__half*)(ws);                          // 3200*256*2 = 1,638,400
    __half* h1T = (__half*)(ws + 1638400);                // 8192*256*2 = 4,194,304
    __half* h2T = (__half*)(ws + 1638400 + 4194304);      // 4,194,304
    __half* h3T = h1T;                                    // 4096*256*2 = 2,097,152
    float* stats = (float*)(ws + 1638400 + 2 * 4194304);  // 4 * 256 floats
    float* gs1 = stats;
    float* gq1 = stats + 256;
    float* gs2 = stats + 512;
    float* gq2 = stats + 768;

    // transpose + stats zero-init fused
    transpose_kernel<<<dim3(IN_DIM / 32, BATCH / 32), dim3(32, 8), 0, stream>>>(
        x, xT, stats);

    // Layer 1: x -> h1 (no input norm)
    popcnt_kernel<false><<<O1_DIM, 256, 0, stream>>>(
        xT, sel1, w1, b1, nullptr, nullptr, nullptr, nullptr, 0.0f, h1T);

    // stats of h1 for layernorm 1
    stats_kernel<<<O1_DIM / 128, 256, 0, stream>>>(h1T, gs1, gq1);

    // Layer 2: layernorm(h1) folded in
    popcnt_kernel<true><<<O1_DIM, 256, 0, stream>>>(
        h1T, sel2, w2, b2, g1, be1, gs1, gq1, 1.0f / (float)O1_DIM, h2T);

    // stats of h2 for layernorm 2
    stats_kernel<<<O1_DIM / 128, 256, 0, stream>>>(h2T, gs2, gq2);

    // Layer 3: layernorm(h2) folded in, writes h3 rows (no atomics)
    popcnt_kernel<true><<<O3_DIM, 256, 0, stream>>>(
        h2T, sel3, w3, b3, g2, be2, gs2, gq2, 1.0f / (float)O1_DIM, h3T);

    // final 16-wide group sum - 8
    final_reduce<<<256, 256, 0, stream>>>(h3T, out);
}